// Round 1
// 190.643 us; speedup vs baseline: 1.0108x; 1.0108x over previous
//
#include <hip/hip_runtime.h>
#include <cstdint>
#include <cstddef>

#define SEQ   2048
#define BBAT  2
#define EMBED 512
#define NH    8
#define HD    64
#define NPOS  34

typedef __bf16 bf16;
typedef __bf16 bf16x8 __attribute__((ext_vector_type(8)));
typedef float  f32x4  __attribute__((ext_vector_type(4)));
typedef int    int32x4 __attribute__((ext_vector_type(4)));

// scale = log2(e)/8 : energy=(qk+bias)/8, computed in exp2 domain.
// ESCALE is folded into Qp at the projection epilogue (z==0), so the attn
// inner loop computes p = exp2(sf + lut[id]) with NO per-element scale mul.
#define ESCALE 0.1803368801111204f

__device__ __forceinline__ f32x4 mfma16(bf16x8 a, bf16x8 b, f32x4 c){
  return __builtin_amdgcn_mfma_f32_16x16x32_bf16(a, b, c, 0, 0, 0);
}

// ---------------- kernel 1: fused prep ----------------
// A: fp32->bf16 convert Q,K,V ; B: weight perms ; C: rel_emb permute (48-row pad)
__global__ __launch_bounds__(256) void k_prep(
    const float* __restrict__ Q, const float* __restrict__ K, const float* __restrict__ V,
    const float* __restrict__ Wq, const float* __restrict__ Wk,
    const float* __restrict__ Wv, const float* __restrict__ Wo,
    const float* __restrict__ RE,
    bf16* __restrict__ Qb, bf16* __restrict__ Kb, bf16* __restrict__ Vb,
    bf16* __restrict__ Wall, bf16* __restrict__ Rb)
{
  const int NCONV = 3*524288;
  const int NW = 196608, NO = 262144;
  int i = blockIdx.x*256 + threadIdx.x;
  if (i < NCONV){
    int tsel = i >> 19, j = i & 524287;
    const float* s = tsel==0 ? Q : (tsel==1 ? K : V);
    bf16* d       = tsel==0 ? Qb : (tsel==1 ? Kb : Vb);
    float4 v = ((const float4*)s)[j];
    union { bf16 e[4]; ushort4 u; } pk;
    pk.e[0]=(bf16)v.x; pk.e[1]=(bf16)v.y; pk.e[2]=(bf16)v.z; pk.e[3]=(bf16)v.w;
    ((ushort4*)d)[j] = pk.u;
  } else {
    int j = i - NCONV;
    if (j < NW){
      int w  = j >> 16;
      int r  = j & 65535;
      int np = r >> 7, c4 = (r & 127) << 2;
      const float* W = (w==0) ? Wq : ((w==1) ? Wk : Wv);
      int src = ((np & 63) << 3) + (np >> 6);
      float4 v = *(const float4*)(W + (size_t)src*512 + c4);
      union { bf16 e[4]; ushort4 u; } pk;
      pk.e[0]=(bf16)v.x; pk.e[1]=(bf16)v.y; pk.e[2]=(bf16)v.z; pk.e[3]=(bf16)v.w;
      *(ushort4*)(Wall + (size_t)w*262144 + (size_t)np*512 + c4) = pk.u;
    } else if (j < NW + NO){
      int jj = j - NW;
      int n = jj >> 9, kp = jj & 511;
      int src = ((kp & 63) << 3) + (kp >> 6);
      Wall[(size_t)3*262144 + (size_t)n*512 + kp] = (bf16)Wo[(size_t)n*512 + src];
    } else {
      int jj = j - NW - NO;
      if (jj < 8*48*64){
        int h  = jj / (48*64);
        int r2 = jj - h*(48*64);
        int p  = r2 >> 6, dd = r2 & 63;
        float v = (p < NPOS) ? RE[(size_t)p*512 + dd*8 + h] : 0.f;
        Rb[jj] = (bf16)v;
      }
    }
  }
}

// ---------------- GEMM 128x64 tile (projections); z==2 writes V transposed ----------------
// z==0 (Q) epilogue multiplies by ESCALE so attn needs no per-element scale.
__global__ __launch_bounds__(256,2) void k_gemm_proj(
    const bf16* __restrict__ Qb, const bf16* __restrict__ Kb, const bf16* __restrict__ Vb,
    const bf16* __restrict__ W,  bf16* __restrict__ Qp, bf16* __restrict__ Kp, bf16* __restrict__ Vt)
{
  const bf16* A  = blockIdx.z==0 ? Qb : (blockIdx.z==1 ? Kb : Vb);
  const bf16* Bw = W + (size_t)blockIdx.z*262144;

  __shared__ __align__(16) bf16 As[128][72];
  __shared__ __align__(16) bf16 Bs[64][72];
  const int t = threadIdx.x;
  const int w = t >> 6, lane = t & 63, l15 = lane & 15, quad = lane >> 4;
  const int wm = (w & 1) * 64, wn = (w >> 1) * 32;
  const int m0 = blockIdx.y * 128, n0 = blockIdx.x * 64;

  f32x4 acc[4][2];
  #pragma unroll
  for (int mt=0; mt<4; ++mt)
    #pragma unroll
    for (int nt=0; nt<2; ++nt) acc[mt][nt] = (f32x4){0.f,0.f,0.f,0.f};

  for (int kt = 0; kt < 512; kt += 64){
    #pragma unroll
    for (int i = 0; i < 4; ++i){
      int lin = t + 256*i;
      int r = lin >> 3, c8 = (lin & 7) << 3;
      *(uint4*)&As[r][c8] = *(const uint4*)(A + (size_t)(m0 + r)*512 + kt + c8);
    }
    #pragma unroll
    for (int i = 0; i < 2; ++i){
      int lin = t + 256*i;
      int r = lin >> 3, c8 = (lin & 7) << 3;
      *(uint4*)&Bs[r][c8] = *(const uint4*)(Bw + (size_t)(n0 + r)*512 + kt + c8);
    }
    __syncthreads();
    #pragma unroll
    for (int ks = 0; ks < 2; ++ks){
      bf16x8 am[4], bn[2];
      #pragma unroll
      for (int x=0;x<4;++x) am[x] = *(const bf16x8*)&As[wm + x*16 + l15][ks*32 + quad*8];
      #pragma unroll
      for (int y=0;y<2;++y) bn[y] = *(const bf16x8*)&Bs[wn + y*16 + l15][ks*32 + quad*8];
      #pragma unroll
      for (int mt=0;mt<4;++mt)
        #pragma unroll
        for (int nt=0;nt<2;++nt)
          acc[mt][nt] = mfma16(am[mt], bn[nt], acc[mt][nt]);
    }
    __syncthreads();
  }

  if (blockIdx.z != 2){
    bf16* C = blockIdx.z==0 ? Qp : Kp;
    const float scl = (blockIdx.z==0) ? ESCALE : 1.0f;
    #pragma unroll
    for (int mt=0;mt<4;++mt)
      #pragma unroll
      for (int r=0;r<4;++r){
        int m = m0 + wm + mt*16 + quad*4 + r;
        #pragma unroll
        for (int nt=0;nt<2;++nt)
          C[(size_t)m*512 + n0 + wn + nt*16 + l15] = (bf16)(acc[mt][nt][r] * scl);
      }
  } else {
    // transpose in-LDS (As region), then coalesced store to Vt (b,h,d,s)
    bf16 (*VT)[136] = (bf16(*)[136])As;    // 64 x 136 bf16 = 17408 B <= 18432
    #pragma unroll
    for (int mt=0;mt<4;++mt)
      #pragma unroll
      for (int r=0;r<4;++r){
        int m = wm + mt*16 + quad*4 + r;
        #pragma unroll
        for (int nt=0;nt<2;++nt)
          VT[wn + nt*16 + l15][m] = (bf16)acc[mt][nt][r];
      }
    __syncthreads();
    const int h = blockIdx.x, b = m0 >> 11, s0 = m0 & 2047;
    const int n = t >> 2, c0 = (t & 3) * 32;
    bf16* dst = Vt + ((size_t)((b*NH + h)*HD + n))*SEQ + s0 + c0;
    #pragma unroll
    for (int i = 0; i < 4; ++i)
      *(uint4*)(dst + i*8) = *(const uint4*)&VT[n][c0 + i*8];
  }
}

// ---------------- GEMM 64x64 tile (output proj, f32 out) ----------------
__global__ __launch_bounds__(256,2) void k_gemm_out(
    const bf16* __restrict__ A, const bf16* __restrict__ Bw, float* __restrict__ C)
{
  __shared__ __align__(16) bf16 As[64][72];
  __shared__ __align__(16) bf16 Bs[64][72];
  const int t = threadIdx.x;
  const int w = t >> 6, lane = t & 63, l15 = lane & 15, quad = lane >> 4;
  const int wm = (w & 1) * 32, wn = (w >> 1) * 32;
  const int m0 = blockIdx.y * 64, n0 = blockIdx.x * 64;

  f32x4 acc[2][2];
  #pragma unroll
  for (int mt=0; mt<2; ++mt)
    #pragma unroll
    for (int nt=0; nt<2; ++nt) acc[mt][nt] = (f32x4){0.f,0.f,0.f,0.f};

  for (int kt = 0; kt < 512; kt += 64){
    #pragma unroll
    for (int i = 0; i < 2; ++i){
      int lin = t + 256*i;
      int r = lin >> 3, c8 = (lin & 7) << 3;
      *(uint4*)&As[r][c8] = *(const uint4*)(A  + (size_t)(m0 + r)*512 + kt + c8);
      *(uint4*)&Bs[r][c8] = *(const uint4*)(Bw + (size_t)(n0 + r)*512 + kt + c8);
    }
    __syncthreads();
    #pragma unroll
    for (int ks = 0; ks < 2; ++ks){
      bf16x8 am[2], bn[2];
      #pragma unroll
      for (int x=0;x<2;++x) am[x] = *(const bf16x8*)&As[wm + x*16 + l15][ks*32 + quad*8];
      #pragma unroll
      for (int y=0;y<2;++y) bn[y] = *(const bf16x8*)&Bs[wn + y*16 + l15][ks*32 + quad*8];
      #pragma unroll
      for (int mt=0;mt<2;++mt)
        #pragma unroll
        for (int nt=0;nt<2;++nt)
          acc[mt][nt] = mfma16(am[mt], bn[nt], acc[mt][nt]);
    }
    __syncthreads();
  }
  #pragma unroll
  for (int mt=0;mt<2;++mt)
    #pragma unroll
    for (int r=0;r<4;++r){
      int m = m0 + wm + mt*16 + quad*4 + r;
      #pragma unroll
      for (int nt=0;nt<2;++nt)
        C[(size_t)m*512 + n0 + wn + nt*16 + l15] = acc[mt][nt][r];
    }
}

// ---------------- flash attention: swapped-QK (S^T), packed Ps, log2 LUT ----------------
// grid (32,8,2) x 256 thr. Wave sub-tiles: QK swapped -> D[kseq][q]: A=K-frag, B=Q-frag.
// Per lane: q = l15 (within mt tile), kseq = quad*4+r  ->  4 consecutive k per lane:
//   * Ps writes pack to ds_write_b64 (8/thr-kt instead of 32 scalar b16)
//   * ids load as int4 (8/thr-kt instead of 32 scalar)
//   * lsum is lane-local per q: 2 shfl_xor (quad bits) instead of 4
// LUT stores Qrel*ESCALE (log2-domain additive bias), padding id -> -1e30 so
// exp2(sf + lut[id]) = 0 implements the mask for free. Qp is pre-scaled by ESCALE.
// PV (A=Ps rows q, B=Vt rows d) is unchanged.
__global__ __launch_bounds__(256,2) void k_attn(
    const bf16* __restrict__ Qp, const bf16* __restrict__ Kp,
    const bf16* __restrict__ Vt, const bf16* __restrict__ Rb,
    const int* __restrict__ ids, bf16* __restrict__ Out)
{
  // LDS: 18432 + 17408 + 17408 + 8960 + 512 = 62720 B -> 2 WG/CU
  __shared__ __align__(16) bf16 Ks[128][72];
  __shared__ __align__(16) bf16 Vs[64][136];
  __shared__ __align__(16) bf16 Ps[64][136];
  __shared__ float lut[64][35];
  __shared__ float lsum_s[128];

  const int t = threadIdx.x;
  const int b = blockIdx.z, h = blockIdx.y;
  const int q0 = blockIdx.x * 64;
  const int w = t >> 6, lane = t & 63, l15 = lane & 15, quad = lane >> 4;
  const int qh = w & 1, kh = w >> 1;

  const size_t idb = (size_t)b*SEQ*SEQ;

  // ---- prefetch tile-0 ids as int4 (latency hidden under LUT build) ----
  int32x4 nid[2][4];
  #pragma unroll
  for (int mt=0; mt<2; ++mt)
    #pragma unroll
    for (int nt=0; nt<4; ++nt)
      nid[mt][nt] = *(const int32x4*)(ids + idb
          + (size_t)(q0 + qh*32 + mt*16 + l15)*SEQ
          + kh*64 + nt*16 + quad*4);

  // ---- build LUT rows via MFMA: lut[q][p] = Qrel*ESCALE (Qp pre-scaled); p==0 -> -1e30 ----
  {
    const bf16* qbrow = Qp + (size_t)(b*SEQ + q0 + w*16 + l15)*EMBED + h*HD;
    bf16x8 ab0 = *(const bf16x8*)(qbrow + quad*8);
    bf16x8 ab1 = *(const bf16x8*)(qbrow + 32 + quad*8);
    const bf16* rh = Rb + h*3072;
    #pragma unroll
    for (int nt = 0; nt < 3; ++nt){
      bf16x8 r0 = *(const bf16x8*)(rh + (nt*16 + l15)*64 + quad*8);
      bf16x8 r1 = *(const bf16x8*)(rh + (nt*16 + l15)*64 + 32 + quad*8);
      f32x4 c = (f32x4){0.f,0.f,0.f,0.f};
      c = mfma16(ab0, r0, c);
      c = mfma16(ab1, r1, c);
      int p = nt*16 + l15;
      if (p < NPOS){
        #pragma unroll
        for (int r = 0; r < 4; ++r)
          lut[w*16 + quad*4 + r][p] = (p == 0) ? -1e30f : c[r];
      }
    }
  }

  // ---- QK B-frags (Q rows, reg-resident): B[n=q][k] ----
  bf16x8 bq[2][2];
  #pragma unroll
  for (int mt = 0; mt < 2; ++mt){
    const bf16* qrow = Qp + (size_t)(b*SEQ + q0 + qh*32 + mt*16 + l15)*EMBED + h*HD;
    bq[mt][0] = *(const bf16x8*)(qrow + quad*8);
    bq[mt][1] = *(const bf16x8*)(qrow + 32 + quad*8);
  }

  const bf16* kbase = Kp + (size_t)b*SEQ*EMBED + h*HD;
  const bf16* vbase = Vt + (size_t)(b*NH + h)*HD*SEQ;

  f32x4 acc[2][2];
  #pragma unroll
  for (int mt=0;mt<2;++mt)
    #pragma unroll
    for (int nt=0;nt<2;++nt) acc[mt][nt] = (f32x4){0.f,0.f,0.f,0.f};
  float lsum[2] = {0.f, 0.f};

  for (int kt = 0; kt < 16; ++kt){
    const int k0 = kt * 128;
    // ---- stage K (128x64) and V^T (64x128) ----
    #pragma unroll
    for (int i = 0; i < 4; ++i){
      int lin = t + 256*i;
      int r = lin >> 3, c8 = (lin & 7) << 3;
      *(uint4*)&Ks[r][c8] = *(const uint4*)(kbase + (size_t)(k0 + r)*EMBED + c8);
    }
    #pragma unroll
    for (int i = 0; i < 4; ++i){
      int lin = t + 256*i;
      int d = lin >> 4, c8 = (lin & 15) << 3;
      *(uint4*)&Vs[d][c8] = *(const uint4*)(vbase + (size_t)d*SEQ + k0 + c8);
    }
    __syncthreads();   // covers LUT build on tile 0

    // ---- bias gathers from LDS LUT (row fixed per lane; indices already resident) ----
    float wv[2][4][4];
    #pragma unroll
    for (int mt = 0; mt < 2; ++mt){
      const float* lr = &lut[qh*32 + mt*16 + l15][0];
      #pragma unroll
      for (int nt = 0; nt < 4; ++nt){
        int32x4 v = nid[mt][nt];
        wv[mt][nt][0] = lr[v[0]];
        wv[mt][nt][1] = lr[v[1]];
        wv[mt][nt][2] = lr[v[2]];
        wv[mt][nt][3] = lr[v[3]];
      }
    }

    // ---- prefetch next tile ids (VMEM flies under MFMA) ----
    if (kt < 15){
      #pragma unroll
      for (int mt = 0; mt < 2; ++mt)
        #pragma unroll
        for (int nt = 0; nt < 4; ++nt)
          nid[mt][nt] = *(const int32x4*)(ids + idb
              + (size_t)(q0 + qh*32 + mt*16 + l15)*SEQ
              + (k0 + 128) + kh*64 + nt*16 + quad*4);
    }

    // ---- QK swapped: D[kseq][q], wave computes 64k x 32q ----
    f32x4 sf[2][4];
    __builtin_amdgcn_s_setprio(1);
    #pragma unroll
    for (int nt = 0; nt < 4; ++nt){
      bf16x8 ak0 = *(const bf16x8*)&Ks[kh*64 + nt*16 + l15][quad*8];
      bf16x8 ak1 = *(const bf16x8*)&Ks[kh*64 + nt*16 + l15][32 + quad*8];
      #pragma unroll
      for (int mt = 0; mt < 2; ++mt){
        f32x4 c = (f32x4){0.f,0.f,0.f,0.f};
        c = mfma16(ak0, bq[mt][0], c);
        c = mfma16(ak1, bq[mt][1], c);
        sf[mt][nt] = c;
      }
    }
    __builtin_amdgcn_s_setprio(0);

    // ---- p = exp2(sf + wv); pack 4 consecutive k -> one b64 write ----
    #pragma unroll
    for (int mt = 0; mt < 2; ++mt){
      #pragma unroll
      for (int nt = 0; nt < 4; ++nt){
        union { bf16 e[4]; uint2 u; } pk;
        float p0 = __builtin_amdgcn_exp2f(sf[mt][nt][0] + wv[mt][nt][0]);
        float p1 = __builtin_amdgcn_exp2f(sf[mt][nt][1] + wv[mt][nt][1]);
        float p2 = __builtin_amdgcn_exp2f(sf[mt][nt][2] + wv[mt][nt][2]);
        float p3 = __builtin_amdgcn_exp2f(sf[mt][nt][3] + wv[mt][nt][3]);
        pk.e[0] = (bf16)p0; pk.e[1] = (bf16)p1;
        pk.e[2] = (bf16)p2; pk.e[3] = (bf16)p3;
        lsum[mt] += (p0 + p1) + (p2 + p3);
        *(uint2*)&Ps[qh*32 + mt*16 + l15][kh*64 + nt*16 + quad*4] = pk.u;
      }
    }
    __syncthreads();   // Ps complete (cross-wave kh halves)

    // ---- PV: wave computes 32q x 32d over full k=128 (unchanged) ----
    __builtin_amdgcn_s_setprio(1);
    #pragma unroll
    for (int kk = 0; kk < 4; ++kk){
      bf16x8 ap[2];
      #pragma unroll
      for (int mt = 0; mt < 2; ++mt)
        ap[mt] = *(const bf16x8*)&Ps[qh*32 + mt*16 + l15][kk*32 + quad*8];
      #pragma unroll
      for (int nt = 0; nt < 2; ++nt){
        bf16x8 bv = *(const bf16x8*)&Vs[kh*32 + nt*16 + l15][kk*32 + quad*8];
        #pragma unroll
        for (int mt = 0; mt < 2; ++mt)
          acc[mt][nt] = mfma16(ap[mt], bv, acc[mt][nt]);
      }
    }
    __builtin_amdgcn_s_setprio(0);
    __syncthreads();   // Ks/Vs/Ps free for next tile
  }

  // ---- lsum: lane-local per q; reduce over quad (lane bits 4,5), publish per kh ----
  #pragma unroll
  for (int mt = 0; mt < 2; ++mt){
    float v = lsum[mt];
    v += __shfl_xor(v, 16);
    v += __shfl_xor(v, 32);
    if (quad == 0) lsum_s[kh*64 + qh*32 + mt*16 + l15] = v;
  }
  __syncthreads();

  // ---- epilogue: normalize, store (b,s,h,d) bf16 ----
  #pragma unroll
  for (int mt = 0; mt < 2; ++mt){
    #pragma unroll
    for (int r = 0; r < 4; ++r){
      int ql = qh*32 + mt*16 + quad*4 + r;
      float inv = __builtin_amdgcn_rcpf(lsum_s[ql] + lsum_s[64 + ql]);
      #pragma unroll
      for (int nt = 0; nt < 2; ++nt){
        int d = kh*32 + nt*16 + l15;
        Out[(size_t)(b*SEQ + q0 + ql)*EMBED + h*HD + d] = (bf16)(acc[mt][nt][r]*inv);
      }
    }
  }
}

// ---------------- launch ----------------
extern "C" void kernel_launch(void* const* d_in, const int* in_sizes, int n_in,
                              void* d_out, int out_size, void* d_ws, size_t ws_size,
                              hipStream_t stream)
{
  (void)in_sizes; (void)n_in; (void)out_size;
  const float* Q  = (const float*)d_in[0];
  const float* K  = (const float*)d_in[1];
  const float* V  = (const float*)d_in[2];
  const int*   ID = (const int*)d_in[3];
  const float* Wq = (const float*)d_in[4];
  const float* Wk = (const float*)d_in[5];
  const float* Wv = (const float*)d_in[6];
  const float* Wo = (const float*)d_in[7];
  const float* RE = (const float*)d_in[8];
  float* out = (float*)d_out;

  const size_t MB = (size_t)1 << 20;
  if (ws_size < 36*MB) return;
  char* ws = (char*)d_ws;
  bf16*  Qb    = (bf16*)(ws + 0*MB);             // dead after proj -> AO overlay
  bf16*  Kb    = (bf16*)(ws + 4*MB);
  bf16*  Vb    = (bf16*)(ws + 8*MB);
  bf16*  Qp    = (bf16*)(ws + 12*MB);
  bf16*  Kp    = (bf16*)(ws + 16*MB);
  bf16*  Vt    = (bf16*)(ws + 20*MB);            // (b,h,d,s) written by proj z==2
  bf16*  Wall  = (bf16*)(ws + 24*MB);            // 2 MB (Wq',Wk',Wv',Wo')
  bf16*  Wop   = Wall + (size_t)3*262144;
  bf16*  Rb    = (bf16*)(ws + 26*MB);            // 48 KB
  bf16*  AO    = (bf16*)(ws + 0*MB);             // overlays Qb

  k_prep      <<<dim3(8032),    256, 0, stream>>>(Q, K, V, Wq, Wk, Wv, Wo, RE,
                                                  Qb, Kb, Vb, Wall, Rb);
  k_gemm_proj <<<dim3(8,32,3),  256, 0, stream>>>(Qb, Kb, Vb, Wall, Qp, Kp, Vt);
  k_attn      <<<dim3(32,8,2),  256, 0, stream>>>(Qp, Kp, Vt, Rb, ID, AO);
  k_gemm_out  <<<dim3(8,64),    256, 0, stream>>>(AO, Wop, out);
}